// Round 5
// baseline (303.879 us; speedup 1.0000x reference)
//
#include <hip/hip_runtime.h>

#define TT 2048
#define TS 2048
#define NB 2
#define CC 512
#define NH 8
#define HD 64
#define NCH 4                 // split-K chunks over keys
#define KCH (TS / NCH)        // 512 keys per chunk
#define NROW (NB * NH * TT)   // 32768 (b,h,q) rows

typedef __attribute__((ext_vector_type(8))) short s8v;
typedef __attribute__((ext_vector_type(8))) __bf16 bf8v;
typedef __attribute__((ext_vector_type(4))) float f4v;
typedef __attribute__((ext_vector_type(4))) unsigned short us4;

static __device__ __forceinline__ unsigned short f2bf(float f) {
  unsigned int u = __builtin_bit_cast(unsigned int, f);
  u += 0x7FFFu + ((u >> 16) & 1u);   // round-to-nearest-even
  return (unsigned short)(u >> 16);
}
static __device__ __forceinline__ float bf2f(unsigned short u) {
  return __builtin_bit_cast(float, (unsigned int)u << 16);
}
static __device__ __forceinline__ bf8v ld_bf8(const unsigned short* p) {
  return __builtin_bit_cast(bf8v, *(const s8v*)p);
}
static __device__ __forceinline__ f4v mfma16(bf8v a, bf8v b, f4v c) {
  return __builtin_amdgcn_mfma_f32_16x16x32_bf16(a, b, c, 0, 0, 0);
}

// ---------------- all-4 weight transpose+convert: WT[n][k] = bf16(W[k][n]) ----------------
__global__ __launch_bounds__(256) void wtrans_k(const float* __restrict__ W0,
    const float* __restrict__ W1, const float* __restrict__ W2, const float* __restrict__ W3,
    unsigned short* __restrict__ T0, unsigned short* __restrict__ T1,
    unsigned short* __restrict__ T2, unsigned short* __restrict__ T3) {
  const float* Ws[4] = {W0, W1, W2, W3};
  unsigned short* Ts[4] = {T0, T1, T2, T3};
  const float* W = Ws[blockIdx.z];
  unsigned short* WT = Ts[blockIdx.z];
  __shared__ float t[64][65];
  int i0 = blockIdx.x * 64, j0 = blockIdx.y * 64;
  int tx = threadIdx.x & 63, ty = threadIdx.x >> 6;
#pragma unroll
  for (int r = 0; r < 16; r++) {
    int li = ty * 16 + r;
    t[li][tx] = W[(size_t)(i0 + li) * CC + j0 + tx];
  }
  __syncthreads();
#pragma unroll
  for (int r = 0; r < 16; r++) {
    int lj = ty * 16 + r;
    WT[(size_t)(j0 + lj) * CC + i0 + tx] = f2bf(t[tx][lj]);
  }
}

// ------- f32->bf16 convert for x/enc, plus mask -> log2-domain penalty -------
__global__ __launch_bounds__(256) void cvt_k(const float* __restrict__ x,
    const float* __restrict__ enc, const int* __restrict__ mask,
    unsigned short* __restrict__ xb, unsigned short* __restrict__ eb,
    float* __restrict__ pinf) {
  size_t t = (size_t)blockIdx.x * 256 + threadIdx.x;
  size_t i = t * 4;
  f4v a = *(const f4v*)(x + i);
  f4v b = *(const f4v*)(enc + i);
  us4 pa, pb;
#pragma unroll
  for (int j = 0; j < 4; j++) { pa[j] = f2bf(a[j]); pb[j] = f2bf(b[j]); }
  *(us4*)(xb + i) = pa;
  *(us4*)(eb + i) = pb;
  if (t < NB * TS) pinf[t] = (mask[t] != 0) ? 0.0f : -1e30f;
}

// ---------------- fused QKV GEMM (depth-2 register prefetch) ----------------
// z=0: Q = xb@Wq (scaled 0.125*log2e), 1: K = eb@Wk, 2: V = eb@Wv (transposed)
__global__ __launch_bounds__(256) void qkv_k(const unsigned short* __restrict__ xb,
    const unsigned short* __restrict__ eb,
    const unsigned short* __restrict__ WqT, const float* __restrict__ bq,
    const unsigned short* __restrict__ WkT, const float* __restrict__ bk,
    const unsigned short* __restrict__ WvT, const float* __restrict__ bv,
    unsigned short* __restrict__ Qb, unsigned short* __restrict__ Kb,
    unsigned short* __restrict__ VTb) {
  int op = blockIdx.z;
  const unsigned short* A = (op == 0) ? xb : eb;
  const unsigned short* WT = (op == 0) ? WqT : (op == 1 ? WkT : WvT);
  const float* bias = (op == 0) ? bq : (op == 1 ? bk : bv);
  int lane = threadIdx.x & 63, wave = threadIdx.x >> 6;
  int quad = lane >> 4, l16 = lane & 15;
  int row0 = blockIdx.x * 64 + wave * 16;
  int n0 = blockIdx.y * 64;
  f4v acc[4] = {{0,0,0,0},{0,0,0,0},{0,0,0,0},{0,0,0,0}};
  const unsigned short* Ap = A + (size_t)(row0 + l16) * CC + quad * 8;
  const unsigned short* Wb = WT + (size_t)(n0 + l16) * CC + quad * 8;
  bf8v a0 = ld_bf8(Ap), a1 = ld_bf8(Ap + 32);
  bf8v b0[4], b1[4];
#pragma unroll
  for (int nt = 0; nt < 4; nt++) {
    b0[nt] = ld_bf8(Wb + (size_t)nt * 16 * CC);
    b1[nt] = ld_bf8(Wb + (size_t)nt * 16 * CC + 32);
  }
  for (int k0 = 0; k0 < CC; k0 += 64) {
    int kp0 = k0 + 64; if (kp0 >= CC) kp0 = 0;
    int kp1 = k0 + 96; if (kp1 >= CC) kp1 = 32;
    bf8v na0 = ld_bf8(Ap + kp0);
    bf8v nb0[4];
#pragma unroll
    for (int nt = 0; nt < 4; nt++) nb0[nt] = ld_bf8(Wb + (size_t)nt * 16 * CC + kp0);
#pragma unroll
    for (int nt = 0; nt < 4; nt++) acc[nt] = mfma16(a0, b0[nt], acc[nt]);
    bf8v na1 = ld_bf8(Ap + kp1);
    bf8v nb1[4];
#pragma unroll
    for (int nt = 0; nt < 4; nt++) nb1[nt] = ld_bf8(Wb + (size_t)nt * 16 * CC + kp1);
#pragma unroll
    for (int nt = 0; nt < 4; nt++) acc[nt] = mfma16(a1, b1[nt], acc[nt]);
    a0 = na0; a1 = na1;
#pragma unroll
    for (int nt = 0; nt < 4; nt++) { b0[nt] = nb0[nt]; b1[nt] = nb1[nt]; }
  }
  const float QSC = 0.125f * 1.44269504088896340736f;  // exp2-domain scale
  float scale = (op == 0) ? QSC : 1.0f;
#pragma unroll
  for (int nt = 0; nt < 4; nt++) {
    int col = n0 + nt * 16 + l16;
    float bcol = bias[col];
    if (op == 2) {
      int rb = row0 + quad * 4;
      int bb = rb >> 11, tt = rb & (TT - 1);
      us4 pk;
#pragma unroll
      for (int r = 0; r < 4; r++) pk[r] = f2bf(acc[nt][r] + bcol);
      *(us4*)(VTb + ((size_t)bb * CC + col) * TS + tt) = pk;
    } else {
      unsigned short* O = (op == 0) ? Qb : Kb;
#pragma unroll
      for (int r = 0; r < 4; r++)
        O[(size_t)(row0 + quad * 4 + r) * CC + col] = f2bf((acc[nt][r] + bcol) * scale);
    }
  }
}

// ---------------- output projection GEMM (depth-2 prefetch, f32 out) ----------------
__global__ __launch_bounds__(256) void gemmo_k(const unsigned short* __restrict__ A,
    const unsigned short* __restrict__ WT, const float* __restrict__ bias,
    float* __restrict__ Cout) {
  int lane = threadIdx.x & 63, wave = threadIdx.x >> 6;
  int quad = lane >> 4, l16 = lane & 15;
  int row0 = blockIdx.x * 64 + wave * 16;
  int n0 = blockIdx.y * 64;
  f4v acc[4] = {{0,0,0,0},{0,0,0,0},{0,0,0,0},{0,0,0,0}};
  const unsigned short* Ap = A + (size_t)(row0 + l16) * CC + quad * 8;
  const unsigned short* Wb = WT + (size_t)(n0 + l16) * CC + quad * 8;
  bf8v a0 = ld_bf8(Ap), a1 = ld_bf8(Ap + 32);
  bf8v b0[4], b1[4];
#pragma unroll
  for (int nt = 0; nt < 4; nt++) {
    b0[nt] = ld_bf8(Wb + (size_t)nt * 16 * CC);
    b1[nt] = ld_bf8(Wb + (size_t)nt * 16 * CC + 32);
  }
  for (int k0 = 0; k0 < CC; k0 += 64) {
    int kp0 = k0 + 64; if (kp0 >= CC) kp0 = 0;
    int kp1 = k0 + 96; if (kp1 >= CC) kp1 = 32;
    bf8v na0 = ld_bf8(Ap + kp0);
    bf8v nb0[4];
#pragma unroll
    for (int nt = 0; nt < 4; nt++) nb0[nt] = ld_bf8(Wb + (size_t)nt * 16 * CC + kp0);
#pragma unroll
    for (int nt = 0; nt < 4; nt++) acc[nt] = mfma16(a0, b0[nt], acc[nt]);
    bf8v na1 = ld_bf8(Ap + kp1);
    bf8v nb1[4];
#pragma unroll
    for (int nt = 0; nt < 4; nt++) nb1[nt] = ld_bf8(Wb + (size_t)nt * 16 * CC + kp1);
#pragma unroll
    for (int nt = 0; nt < 4; nt++) acc[nt] = mfma16(a1, b1[nt], acc[nt]);
    a0 = na0; a1 = na1;
#pragma unroll
    for (int nt = 0; nt < 4; nt++) { b0[nt] = nb0[nt]; b1[nt] = nb1[nt]; }
  }
#pragma unroll
  for (int nt = 0; nt < 4; nt++) {
    int col = n0 + nt * 16 + l16;
    float bcol = bias[col];
#pragma unroll
    for (int r = 0; r < 4; r++)
      Cout[(size_t)(row0 + quad * 4 + r) * CC + col] = acc[nt][r] + bcol;
  }
}

// ---------------- split-K flash attention: max-free exp2 softmax + K prefetch ----------------
// grid (TT/64, NB*NH, NCH), block 256. Lane owns q=l16; 16 scores in-lane.
__global__ __launch_bounds__(256) void attn_k(const unsigned short* __restrict__ Q,
    const unsigned short* __restrict__ K, const unsigned short* __restrict__ VT,
    const float* __restrict__ pinf, unsigned short* __restrict__ Op,
    float* __restrict__ Lp) {
  __shared__ unsigned short Pl[4][16][72];  // wave-private P[q][key], +8 pad
  int lane = threadIdx.x & 63, wave = threadIdx.x >> 6;
  int quad = lane >> 4, l16 = lane & 15;
  int bh = blockIdx.y;
  int b = bh >> 3, h = bh & 7;
  int chunk = blockIdx.z;
  int q0 = blockIdx.x * 64 + wave * 16;

  const unsigned short* qp = Q + (size_t)(b * TT + q0 + l16) * CC + h * HD + quad * 8;
  bf8v qa0 = ld_bf8(qp), qa1 = ld_bf8(qp + 32);

  f4v o[4] = {{0,0,0,0},{0,0,0,0},{0,0,0,0},{0,0,0,0}};
  f4v lsum = {0, 0, 0, 0};
  const float* prow = pinf + (size_t)b * TS + chunk * KCH;
  const unsigned short* Kbase =
      K + (size_t)(b * TS + chunk * KCH) * CC + h * HD + quad * 8;
  const unsigned short* Vbase =
      VT + ((size_t)b * CC + h * HD) * TS + chunk * KCH + quad * 8;

  // preload K frags for tile 0
  bf8v kf[4][2];
#pragma unroll
  for (int nt = 0; nt < 4; nt++) {
    const unsigned short* kp = Kbase + (size_t)(nt * 16 + l16) * CC;
    kf[nt][0] = ld_bf8(kp);
    kf[nt][1] = ld_bf8(kp + 32);
  }

  for (int kt = 0; kt < KCH; kt += 64) {
    // V frags for THIS tile: issue early (used after the exp/LDS chain)
    bf8v vf[4][2];
#pragma unroll
    for (int dt = 0; dt < 4; dt++) {
      const unsigned short* vp = Vbase + (size_t)(dt * 16 + l16) * TS + kt;
      vf[dt][0] = ld_bf8(vp);
      vf[dt][1] = ld_bf8(vp + 32);
    }
    // S^T = K·Q^T + pen (log2 domain; penalty as accumulator init)
    f4v s[4];
#pragma unroll
    for (int nt = 0; nt < 4; nt++) {
      f4v z = *(const f4v*)(prow + kt + nt * 16 + quad * 4);
      z = mfma16(kf[nt][0], qa0, z);
      z = mfma16(kf[nt][1], qa1, z);
      s[nt] = z;
    }
    // prefetch next tile's K frags (full-iteration distance)
    int ktn = kt + 64; if (ktn >= KCH) ktn = 0;
    bf8v kn[4][2];
#pragma unroll
    for (int nt = 0; nt < 4; nt++) {
      const unsigned short* kp = Kbase + (size_t)(ktn + nt * 16 + l16) * CC;
      kn[nt][0] = ld_bf8(kp);
      kn[nt][1] = ld_bf8(kp + 32);
    }
    // max-free softmax: P = exp2(s), accumulate l per-lane
#pragma unroll
    for (int nt = 0; nt < 4; nt++) {
      us4 pk;
#pragma unroll
      for (int r = 0; r < 4; r++) {
        float p = __builtin_amdgcn_exp2f(s[nt][r]);
        s[nt][r] = p;
        pk[r] = f2bf(p);
      }
      lsum += s[nt];
      *(us4*)&Pl[wave][l16][nt * 16 + quad * 4] = pk;
    }
    bf8v pb0 = ld_bf8(&Pl[wave][l16][quad * 8]);
    bf8v pb1 = ld_bf8(&Pl[wave][l16][32 + quad * 8]);
    // O^T += V^T·P^T
#pragma unroll
    for (int dt = 0; dt < 4; dt++) {
      o[dt] = mfma16(vf[dt][0], pb0, o[dt]);
      o[dt] = mfma16(vf[dt][1], pb1, o[dt]);
    }
#pragma unroll
    for (int nt = 0; nt < 4; nt++) { kf[nt][0] = kn[nt][0]; kf[nt][1] = kn[nt][1]; }
  }
  float l = (lsum[0] + lsum[1]) + (lsum[2] + lsum[3]);
  l += __shfl_xor(l, 16, 64);
  l += __shfl_xor(l, 32, 64);
  // store unnormalized partials (packed 8B)
  int rowb = (b * NH + h) * TT + q0;
  size_t obase = (size_t)chunk * NROW * HD + (size_t)(rowb + l16) * HD;
#pragma unroll
  for (int dt = 0; dt < 4; dt++) {
    us4 pk;
#pragma unroll
    for (int r = 0; r < 4; r++) pk[r] = f2bf(o[dt][r]);
    *(us4*)&Op[obase + dt * 16 + quad * 4] = pk;
  }
  if (quad == 0) Lp[(size_t)chunk * NROW + rowb + l16] = l;
}

// ---------------- split-K combine: plain sums (shared exp2 domain) ----------------
__global__ __launch_bounds__(256) void combine_k(const unsigned short* __restrict__ Op,
    const float* __restrict__ Lp, unsigned short* __restrict__ Attb) {
  int row = blockIdx.x * 4 + (threadIdx.x >> 6);
  int d = threadIdx.x & 63;
  float L = 0.f, o = 0.f;
#pragma unroll
  for (int c = 0; c < NCH; c++) {
    L += Lp[(size_t)c * NROW + row];
    o += bf2f(Op[(size_t)c * NROW * HD + (size_t)row * HD + d]);
  }
  int b = row >> 14, h = (row >> 11) & 7, q = row & (TT - 1);
  Attb[((size_t)(b * TT + q)) * CC + h * HD + d] = f2bf(o / L);
}

extern "C" void kernel_launch(void* const* d_in, const int* in_sizes, int n_in,
                              void* d_out, int out_size, void* d_ws, size_t ws_size,
                              hipStream_t stream) {
  const float* x   = (const float*)d_in[0];
  const float* enc = (const float*)d_in[1];
  const int*   msk = (const int*)d_in[2];
  const float* Wq  = (const float*)d_in[3];
  const float* bq  = (const float*)d_in[4];
  const float* Wk  = (const float*)d_in[5];
  const float* bk  = (const float*)d_in[6];
  const float* Wv  = (const float*)d_in[7];
  const float* bv  = (const float*)d_in[8];
  const float* Wo  = (const float*)d_in[9];
  const float* bo  = (const float*)d_in[10];
  float* out = (float*)d_out;

  char* ws = (char*)d_ws;
  const size_t MB = 1024 * 1024;
  unsigned short* WqT  = (unsigned short*)(ws);                 // 512 KB
  unsigned short* WkT  = (unsigned short*)(ws + 512 * 1024);
  unsigned short* WvT  = (unsigned short*)(ws + 1024 * 1024);
  unsigned short* WoT  = (unsigned short*)(ws + 1536 * 1024);
  unsigned short* Qb   = (unsigned short*)(ws + 2 * MB);        // 4 MB
  unsigned short* Kb   = (unsigned short*)(ws + 6 * MB);        // 4 MB
  unsigned short* VTb  = (unsigned short*)(ws + 10 * MB);       // 4 MB
  unsigned short* Attb = (unsigned short*)(ws + 14 * MB);       // 4 MB
  // xb/eb live only until the QKV GEMM; Opart overlays them afterwards
  unsigned short* xb   = (unsigned short*)(ws + 18 * MB);       // 4 MB
  unsigned short* eb   = (unsigned short*)(ws + 22 * MB);       // 4 MB
  unsigned short* Opart = (unsigned short*)(ws + 18 * MB);      // 16 MB (overlay)
  float* Lp   = (float*)(ws + 34 * MB);                         // 512 KB
  float* pinf = (float*)(ws + 35 * MB);                         // 16 KB

  dim3 blk(256);
  wtrans_k<<<dim3(8, 8, 4), blk, 0, stream>>>(Wq, Wk, Wv, Wo, WqT, WkT, WvT, WoT);
  cvt_k<<<dim3(2048), blk, 0, stream>>>(x, enc, msk, xb, eb, pinf);

  qkv_k<<<dim3(64, 8, 3), blk, 0, stream>>>(xb, eb, WqT, bq, WkT, bk, WvT, bv,
                                            Qb, Kb, VTb);

  attn_k<<<dim3(TT / 64, NB * NH, NCH), blk, 0, stream>>>(Qb, Kb, VTb, pinf,
                                                          Opart, Lp);
  combine_k<<<dim3(NROW / 4), blk, 0, stream>>>(Opart, Lp, Attb);

  gemmo_k<<<dim3(64, 8), blk, 0, stream>>>(Attb, WoT, bo, out);
}

// Round 6
// 303.590 us; speedup vs baseline: 1.0009x; 1.0009x over previous
//
#include <hip/hip_runtime.h>

#define TT 2048
#define TS 2048
#define NB 2
#define CC 512
#define NH 8
#define HD 64
#define NCH 4                 // split-K chunks over keys
#define KCH (TS / NCH)        // 512 keys per chunk
#define NROW (NB * NH * TT)   // 32768 (b,h,q) rows

typedef __attribute__((ext_vector_type(8))) short s8v;
typedef __attribute__((ext_vector_type(8))) __bf16 bf8v;
typedef __attribute__((ext_vector_type(4))) float f4v;
typedef __attribute__((ext_vector_type(4))) unsigned short us4;

static __device__ __forceinline__ unsigned short f2bf(float f) {
  unsigned int u = __builtin_bit_cast(unsigned int, f);
  u += 0x7FFFu + ((u >> 16) & 1u);   // round-to-nearest-even
  return (unsigned short)(u >> 16);
}
static __device__ __forceinline__ float bf2f(unsigned short u) {
  return __builtin_bit_cast(float, (unsigned int)u << 16);
}
static __device__ __forceinline__ bf8v ld_bf8(const unsigned short* p) {
  return __builtin_bit_cast(bf8v, *(const s8v*)p);
}
static __device__ __forceinline__ f4v mfma16(bf8v a, bf8v b, f4v c) {
  return __builtin_amdgcn_mfma_f32_16x16x32_bf16(a, b, c, 0, 0, 0);
}

// ---------------- all-4 weight transpose+convert: WT[n][k] = bf16(W[k][n]) ----------------
__global__ __launch_bounds__(256) void wtrans_k(const float* __restrict__ W0,
    const float* __restrict__ W1, const float* __restrict__ W2, const float* __restrict__ W3,
    unsigned short* __restrict__ T0, unsigned short* __restrict__ T1,
    unsigned short* __restrict__ T2, unsigned short* __restrict__ T3) {
  const float* Ws[4] = {W0, W1, W2, W3};
  unsigned short* Ts[4] = {T0, T1, T2, T3};
  const float* W = Ws[blockIdx.z];
  unsigned short* WT = Ts[blockIdx.z];
  __shared__ float t[64][65];
  int i0 = blockIdx.x * 64, j0 = blockIdx.y * 64;
  int tx = threadIdx.x & 63, ty = threadIdx.x >> 6;
#pragma unroll
  for (int r = 0; r < 16; r++) {
    int li = ty * 16 + r;
    t[li][tx] = W[(size_t)(i0 + li) * CC + j0 + tx];
  }
  __syncthreads();
#pragma unroll
  for (int r = 0; r < 16; r++) {
    int lj = ty * 16 + r;
    WT[(size_t)(j0 + lj) * CC + i0 + tx] = f2bf(t[tx][lj]);
  }
}

// ------- f32->bf16 convert for x/enc, plus mask -> log2-domain penalty -------
__global__ __launch_bounds__(256) void cvt_k(const float* __restrict__ x,
    const float* __restrict__ enc, const int* __restrict__ mask,
    unsigned short* __restrict__ xb, unsigned short* __restrict__ eb,
    float* __restrict__ pinf) {
  size_t t = (size_t)blockIdx.x * 256 + threadIdx.x;
  size_t i = t * 4;
  f4v a = *(const f4v*)(x + i);
  f4v b = *(const f4v*)(enc + i);
  us4 pa, pb;
#pragma unroll
  for (int j = 0; j < 4; j++) { pa[j] = f2bf(a[j]); pb[j] = f2bf(b[j]); }
  *(us4*)(xb + i) = pa;
  *(us4*)(eb + i) = pb;
  if (t < NB * TS) pinf[t] = (mask[t] != 0) ? 0.0f : -1e30f;
}

// ---------------- fused QKV GEMM (depth-2 register prefetch) ----------------
// z=0: Q = xb@Wq (scaled 0.125*log2e), 1: K = eb@Wk, 2: V = eb@Wv (transposed)
__global__ __launch_bounds__(256) void qkv_k(const unsigned short* __restrict__ xb,
    const unsigned short* __restrict__ eb,
    const unsigned short* __restrict__ WqT, const float* __restrict__ bq,
    const unsigned short* __restrict__ WkT, const float* __restrict__ bk,
    const unsigned short* __restrict__ WvT, const float* __restrict__ bv,
    unsigned short* __restrict__ Qb, unsigned short* __restrict__ Kb,
    unsigned short* __restrict__ VTb) {
  int op = blockIdx.z;
  const unsigned short* A = (op == 0) ? xb : eb;
  const unsigned short* WT = (op == 0) ? WqT : (op == 1 ? WkT : WvT);
  const float* bias = (op == 0) ? bq : (op == 1 ? bk : bv);
  int lane = threadIdx.x & 63, wave = threadIdx.x >> 6;
  int quad = lane >> 4, l16 = lane & 15;
  int row0 = blockIdx.x * 64 + wave * 16;
  int n0 = blockIdx.y * 64;
  f4v acc[4] = {{0,0,0,0},{0,0,0,0},{0,0,0,0},{0,0,0,0}};
  const unsigned short* Ap = A + (size_t)(row0 + l16) * CC + quad * 8;
  const unsigned short* Wb = WT + (size_t)(n0 + l16) * CC + quad * 8;
  bf8v a0 = ld_bf8(Ap), a1 = ld_bf8(Ap + 32);
  bf8v b0[4], b1[4];
#pragma unroll
  for (int nt = 0; nt < 4; nt++) {
    b0[nt] = ld_bf8(Wb + (size_t)nt * 16 * CC);
    b1[nt] = ld_bf8(Wb + (size_t)nt * 16 * CC + 32);
  }
  for (int k0 = 0; k0 < CC; k0 += 64) {
    int kp0 = k0 + 64; if (kp0 >= CC) kp0 = 0;
    int kp1 = k0 + 96; if (kp1 >= CC) kp1 = 32;
    bf8v na0 = ld_bf8(Ap + kp0);
    bf8v nb0[4];
#pragma unroll
    for (int nt = 0; nt < 4; nt++) nb0[nt] = ld_bf8(Wb + (size_t)nt * 16 * CC + kp0);
#pragma unroll
    for (int nt = 0; nt < 4; nt++) acc[nt] = mfma16(a0, b0[nt], acc[nt]);
    bf8v na1 = ld_bf8(Ap + kp1);
    bf8v nb1[4];
#pragma unroll
    for (int nt = 0; nt < 4; nt++) nb1[nt] = ld_bf8(Wb + (size_t)nt * 16 * CC + kp1);
#pragma unroll
    for (int nt = 0; nt < 4; nt++) acc[nt] = mfma16(a1, b1[nt], acc[nt]);
    a0 = na0; a1 = na1;
#pragma unroll
    for (int nt = 0; nt < 4; nt++) { b0[nt] = nb0[nt]; b1[nt] = nb1[nt]; }
  }
  const float QSC = 0.125f * 1.44269504088896340736f;  // exp2-domain scale
  float scale = (op == 0) ? QSC : 1.0f;
#pragma unroll
  for (int nt = 0; nt < 4; nt++) {
    int col = n0 + nt * 16 + l16;
    float bcol = bias[col];
    if (op == 2) {
      int rb = row0 + quad * 4;
      int bb = rb >> 11, tt = rb & (TT - 1);
      us4 pk;
#pragma unroll
      for (int r = 0; r < 4; r++) pk[r] = f2bf(acc[nt][r] + bcol);
      *(us4*)(VTb + ((size_t)bb * CC + col) * TS + tt) = pk;
    } else {
      unsigned short* O = (op == 0) ? Qb : Kb;
#pragma unroll
      for (int r = 0; r < 4; r++)
        O[(size_t)(row0 + quad * 4 + r) * CC + col] = f2bf((acc[nt][r] + bcol) * scale);
    }
  }
}

// ---------------- output projection GEMM (depth-2 prefetch, f32 out) ----------------
__global__ __launch_bounds__(256) void gemmo_k(const unsigned short* __restrict__ A,
    const unsigned short* __restrict__ WT, const float* __restrict__ bias,
    float* __restrict__ Cout) {
  int lane = threadIdx.x & 63, wave = threadIdx.x >> 6;
  int quad = lane >> 4, l16 = lane & 15;
  int row0 = blockIdx.x * 64 + wave * 16;
  int n0 = blockIdx.y * 64;
  f4v acc[4] = {{0,0,0,0},{0,0,0,0},{0,0,0,0},{0,0,0,0}};
  const unsigned short* Ap = A + (size_t)(row0 + l16) * CC + quad * 8;
  const unsigned short* Wb = WT + (size_t)(n0 + l16) * CC + quad * 8;
  bf8v a0 = ld_bf8(Ap), a1 = ld_bf8(Ap + 32);
  bf8v b0[4], b1[4];
#pragma unroll
  for (int nt = 0; nt < 4; nt++) {
    b0[nt] = ld_bf8(Wb + (size_t)nt * 16 * CC);
    b1[nt] = ld_bf8(Wb + (size_t)nt * 16 * CC + 32);
  }
  for (int k0 = 0; k0 < CC; k0 += 64) {
    int kp0 = k0 + 64; if (kp0 >= CC) kp0 = 0;
    int kp1 = k0 + 96; if (kp1 >= CC) kp1 = 32;
    bf8v na0 = ld_bf8(Ap + kp0);
    bf8v nb0[4];
#pragma unroll
    for (int nt = 0; nt < 4; nt++) nb0[nt] = ld_bf8(Wb + (size_t)nt * 16 * CC + kp0);
#pragma unroll
    for (int nt = 0; nt < 4; nt++) acc[nt] = mfma16(a0, b0[nt], acc[nt]);
    bf8v na1 = ld_bf8(Ap + kp1);
    bf8v nb1[4];
#pragma unroll
    for (int nt = 0; nt < 4; nt++) nb1[nt] = ld_bf8(Wb + (size_t)nt * 16 * CC + kp1);
#pragma unroll
    for (int nt = 0; nt < 4; nt++) acc[nt] = mfma16(a1, b1[nt], acc[nt]);
    a0 = na0; a1 = na1;
#pragma unroll
    for (int nt = 0; nt < 4; nt++) { b0[nt] = nb0[nt]; b1[nt] = nb1[nt]; }
  }
#pragma unroll
  for (int nt = 0; nt < 4; nt++) {
    int col = n0 + nt * 16 + l16;
    float bcol = bias[col];
#pragma unroll
    for (int r = 0; r < 4; r++)
      Cout[(size_t)(row0 + quad * 4 + r) * CC + col] = acc[nt][r] + bcol;
  }
}

// ---------------- split-K flash attention, XCD-pinned ----------------
// 1-D grid of 2048: id = bh + 16*(qblk + 32*chunk)  =>  id%8 == bh%8,
// so all 128 WGs of one (b,h) land on one XCD (round-robin dispatch) and
// its 512KB K+V slice stays L2-resident (2 pairs/XCD = 1MB << 4MB).
__global__ __launch_bounds__(256) void attn_k(const unsigned short* __restrict__ Q,
    const unsigned short* __restrict__ K, const unsigned short* __restrict__ VT,
    const float* __restrict__ pinf, unsigned short* __restrict__ Op,
    float* __restrict__ Lp) {
  __shared__ unsigned short Pl[4][16][72];  // wave-private P[q][key], +8 pad
  int lane = threadIdx.x & 63, wave = threadIdx.x >> 6;
  int quad = lane >> 4, l16 = lane & 15;
  int id = blockIdx.x;
  int bh = id & 15;
  int rest = id >> 4;
  int qblk = rest & 31;
  int chunk = rest >> 5;
  int b = bh >> 3, h = bh & 7;
  int q0 = qblk * 64 + wave * 16;

  const unsigned short* qp = Q + (size_t)(b * TT + q0 + l16) * CC + h * HD + quad * 8;
  bf8v qa0 = ld_bf8(qp), qa1 = ld_bf8(qp + 32);

  f4v o[4] = {{0,0,0,0},{0,0,0,0},{0,0,0,0},{0,0,0,0}};
  f4v lsum = {0, 0, 0, 0};
  const float* prow = pinf + (size_t)b * TS + chunk * KCH;
  const unsigned short* Kbase =
      K + (size_t)(b * TS + chunk * KCH) * CC + h * HD + quad * 8;
  const unsigned short* Vbase =
      VT + ((size_t)b * CC + h * HD) * TS + chunk * KCH + quad * 8;

  // preload K frags for tile 0
  bf8v kf[4][2];
#pragma unroll
  for (int nt = 0; nt < 4; nt++) {
    const unsigned short* kp = Kbase + (size_t)(nt * 16 + l16) * CC;
    kf[nt][0] = ld_bf8(kp);
    kf[nt][1] = ld_bf8(kp + 32);
  }

  for (int kt = 0; kt < KCH; kt += 64) {
    // V frags for THIS tile: issue early (used after the exp/LDS chain)
    bf8v vf[4][2];
#pragma unroll
    for (int dt = 0; dt < 4; dt++) {
      const unsigned short* vp = Vbase + (size_t)(dt * 16 + l16) * TS + kt;
      vf[dt][0] = ld_bf8(vp);
      vf[dt][1] = ld_bf8(vp + 32);
    }
    // S^T = K·Q^T + pen (log2 domain; penalty as accumulator init)
    f4v s[4];
#pragma unroll
    for (int nt = 0; nt < 4; nt++) {
      f4v z = *(const f4v*)(prow + kt + nt * 16 + quad * 4);
      z = mfma16(kf[nt][0], qa0, z);
      z = mfma16(kf[nt][1], qa1, z);
      s[nt] = z;
    }
    // prefetch next tile's K frags (full-iteration distance)
    int ktn = kt + 64; if (ktn >= KCH) ktn = 0;
    bf8v kn[4][2];
#pragma unroll
    for (int nt = 0; nt < 4; nt++) {
      const unsigned short* kp = Kbase + (size_t)(ktn + nt * 16 + l16) * CC;
      kn[nt][0] = ld_bf8(kp);
      kn[nt][1] = ld_bf8(kp + 32);
    }
    // max-free softmax: P = exp2(s), accumulate l per-lane
#pragma unroll
    for (int nt = 0; nt < 4; nt++) {
      us4 pk;
#pragma unroll
      for (int r = 0; r < 4; r++) {
        float p = __builtin_amdgcn_exp2f(s[nt][r]);
        s[nt][r] = p;
        pk[r] = f2bf(p);
      }
      lsum += s[nt];
      *(us4*)&Pl[wave][l16][nt * 16 + quad * 4] = pk;
    }
    bf8v pb0 = ld_bf8(&Pl[wave][l16][quad * 8]);
    bf8v pb1 = ld_bf8(&Pl[wave][l16][32 + quad * 8]);
    // O^T += V^T·P^T
#pragma unroll
    for (int dt = 0; dt < 4; dt++) {
      o[dt] = mfma16(vf[dt][0], pb0, o[dt]);
      o[dt] = mfma16(vf[dt][1], pb1, o[dt]);
    }
#pragma unroll
    for (int nt = 0; nt < 4; nt++) { kf[nt][0] = kn[nt][0]; kf[nt][1] = kn[nt][1]; }
  }
  float l = (lsum[0] + lsum[1]) + (lsum[2] + lsum[3]);
  l += __shfl_xor(l, 16, 64);
  l += __shfl_xor(l, 32, 64);
  // store unnormalized partials (packed 8B)
  int rowb = (b * NH + h) * TT + q0;
  size_t obase = (size_t)chunk * NROW * HD + (size_t)(rowb + l16) * HD;
#pragma unroll
  for (int dt = 0; dt < 4; dt++) {
    us4 pk;
#pragma unroll
    for (int r = 0; r < 4; r++) pk[r] = f2bf(o[dt][r]);
    *(us4*)&Op[obase + dt * 16 + quad * 4] = pk;
  }
  if (quad == 0) Lp[(size_t)chunk * NROW + rowb + l16] = l;
}

// ---------------- split-K combine: plain sums (shared exp2 domain) ----------------
__global__ __launch_bounds__(256) void combine_k(const unsigned short* __restrict__ Op,
    const float* __restrict__ Lp, unsigned short* __restrict__ Attb) {
  int row = blockIdx.x * 4 + (threadIdx.x >> 6);
  int d = threadIdx.x & 63;
  float L = 0.f, o = 0.f;
#pragma unroll
  for (int c = 0; c < NCH; c++) {
    L += Lp[(size_t)c * NROW + row];
    o += bf2f(Op[(size_t)c * NROW * HD + (size_t)row * HD + d]);
  }
  int b = row >> 14, h = (row >> 11) & 7, q = row & (TT - 1);
  Attb[((size_t)(b * TT + q)) * CC + h * HD + d] = f2bf(o / L);
}

extern "C" void kernel_launch(void* const* d_in, const int* in_sizes, int n_in,
                              void* d_out, int out_size, void* d_ws, size_t ws_size,
                              hipStream_t stream) {
  const float* x   = (const float*)d_in[0];
  const float* enc = (const float*)d_in[1];
  const int*   msk = (const int*)d_in[2];
  const float* Wq  = (const float*)d_in[3];
  const float* bq  = (const float*)d_in[4];
  const float* Wk  = (const float*)d_in[5];
  const float* bk  = (const float*)d_in[6];
  const float* Wv  = (const float*)d_in[7];
  const float* bv  = (const float*)d_in[8];
  const float* Wo  = (const float*)d_in[9];
  const float* bo  = (const float*)d_in[10];
  float* out = (float*)d_out;

  char* ws = (char*)d_ws;
  const size_t MB = 1024 * 1024;
  unsigned short* WqT  = (unsigned short*)(ws);                 // 512 KB
  unsigned short* WkT  = (unsigned short*)(ws + 512 * 1024);
  unsigned short* WvT  = (unsigned short*)(ws + 1024 * 1024);
  unsigned short* WoT  = (unsigned short*)(ws + 1536 * 1024);
  unsigned short* Qb   = (unsigned short*)(ws + 2 * MB);        // 4 MB
  unsigned short* Kb   = (unsigned short*)(ws + 6 * MB);        // 4 MB
  unsigned short* VTb  = (unsigned short*)(ws + 10 * MB);       // 4 MB
  unsigned short* Attb = (unsigned short*)(ws + 14 * MB);       // 4 MB
  // xb/eb live only until the QKV GEMM; Opart overlays them afterwards
  unsigned short* xb   = (unsigned short*)(ws + 18 * MB);       // 4 MB
  unsigned short* eb   = (unsigned short*)(ws + 22 * MB);       // 4 MB
  unsigned short* Opart = (unsigned short*)(ws + 18 * MB);      // 16 MB (overlay)
  float* Lp   = (float*)(ws + 34 * MB);                         // 512 KB
  float* pinf = (float*)(ws + 35 * MB);                         // 16 KB

  dim3 blk(256);
  wtrans_k<<<dim3(8, 8, 4), blk, 0, stream>>>(Wq, Wk, Wv, Wo, WqT, WkT, WvT, WoT);
  cvt_k<<<dim3(2048), blk, 0, stream>>>(x, enc, msk, xb, eb, pinf);

  qkv_k<<<dim3(64, 8, 3), blk, 0, stream>>>(xb, eb, WqT, bq, WkT, bk, WvT, bv,
                                            Qb, Kb, VTb);

  attn_k<<<dim3(2048), blk, 0, stream>>>(Qb, Kb, VTb, pinf, Opart, Lp);
  combine_k<<<dim3(NROW / 4), blk, 0, stream>>>(Opart, Lp, Attb);

  gemmo_k<<<dim3(64, 8), blk, 0, stream>>>(Attb, WoT, bo, out);
}

// Round 7
// 152.215 us; speedup vs baseline: 1.9964x; 1.9945x over previous
//
#include <hip/hip_runtime.h>

#define TT 2048
#define TS 2048
#define NB 2
#define CC 512
#define NH 8
#define HD 64
#define NCH 4                 // split-K chunks over keys
#define KCH (TS / NCH)        // 512 keys per chunk
#define NROW (NB * NH * TT)   // 32768 (b,h,q) rows

typedef __attribute__((ext_vector_type(8))) short s8v;
typedef __attribute__((ext_vector_type(8))) __bf16 bf8v;
typedef __attribute__((ext_vector_type(4))) float f4v;
typedef __attribute__((ext_vector_type(4))) unsigned short us4;

static __device__ __forceinline__ unsigned short f2bf(float f) {
  unsigned int u = __builtin_bit_cast(unsigned int, f);
  u += 0x7FFFu + ((u >> 16) & 1u);   // round-to-nearest-even
  return (unsigned short)(u >> 16);
}
static __device__ __forceinline__ float bf2f(unsigned short u) {
  return __builtin_bit_cast(float, (unsigned int)u << 16);
}
static __device__ __forceinline__ bf8v ld_bf8(const unsigned short* p) {
  return __builtin_bit_cast(bf8v, *(const s8v*)p);
}
static __device__ __forceinline__ f4v mfma16(bf8v a, bf8v b, f4v c) {
  return __builtin_amdgcn_mfma_f32_16x16x32_bf16(a, b, c, 0, 0, 0);
}
// async global->LDS, 16B per lane. LDS dest = wave-uniform base + lane*16.
static __device__ __forceinline__ void gll16(const unsigned short* g,
                                             unsigned short* l) {
  __builtin_amdgcn_global_load_lds(
      (const __attribute__((address_space(1))) unsigned int*)g,
      (__attribute__((address_space(3))) unsigned int*)l, 16, 0, 0);
}

// ---------------- all-4 weight transpose+convert: WT[n][k] = bf16(W[k][n]) ----------------
__global__ __launch_bounds__(256) void wtrans_k(const float* __restrict__ W0,
    const float* __restrict__ W1, const float* __restrict__ W2, const float* __restrict__ W3,
    unsigned short* __restrict__ T0, unsigned short* __restrict__ T1,
    unsigned short* __restrict__ T2, unsigned short* __restrict__ T3) {
  const float* Ws[4] = {W0, W1, W2, W3};
  unsigned short* Ts[4] = {T0, T1, T2, T3};
  const float* W = Ws[blockIdx.z];
  unsigned short* WT = Ts[blockIdx.z];
  __shared__ float t[64][65];
  int i0 = blockIdx.x * 64, j0 = blockIdx.y * 64;
  int tx = threadIdx.x & 63, ty = threadIdx.x >> 6;
#pragma unroll
  for (int r = 0; r < 16; r++) {
    int li = ty * 16 + r;
    t[li][tx] = W[(size_t)(i0 + li) * CC + j0 + tx];
  }
  __syncthreads();
#pragma unroll
  for (int r = 0; r < 16; r++) {
    int lj = ty * 16 + r;
    WT[(size_t)(j0 + lj) * CC + i0 + tx] = f2bf(t[tx][lj]);
  }
}

// ------- f32->bf16 convert for x/enc, plus mask -> log2-domain penalty -------
__global__ __launch_bounds__(256) void cvt_k(const float* __restrict__ x,
    const float* __restrict__ enc, const int* __restrict__ mask,
    unsigned short* __restrict__ xb, unsigned short* __restrict__ eb,
    float* __restrict__ pinf) {
  size_t t = (size_t)blockIdx.x * 256 + threadIdx.x;
  size_t i = t * 4;
  f4v a = *(const f4v*)(x + i);
  f4v b = *(const f4v*)(enc + i);
  us4 pa, pb;
#pragma unroll
  for (int j = 0; j < 4; j++) { pa[j] = f2bf(a[j]); pb[j] = f2bf(b[j]); }
  *(us4*)(xb + i) = pa;
  *(us4*)(eb + i) = pb;
  if (t < NB * TS) pinf[t] = (mask[t] != 0) ? 0.0f : -1e30f;
}

// ---------------- 128x64-tile GEMM, gll-staged, double-buffered LDS ----------------
// op = blockIdx.z + zbase: 0=Q (scale), 1=K, 2=V (transposed store), 3=O (f32 out)
// A,W rows are 512 shorts; tiles staged as rows of 64 shorts (128B), XOR-swizzled
// in 16B chunks so ds_read_b128 frag reads are bank-uniform.
__global__ __launch_bounds__(256) void gemm128_k(
    const unsigned short* __restrict__ xb, const unsigned short* __restrict__ eb,
    const unsigned short* __restrict__ Attb,
    const unsigned short* __restrict__ WqT, const unsigned short* __restrict__ WkT,
    const unsigned short* __restrict__ WvT, const unsigned short* __restrict__ WoT,
    const float* __restrict__ bq, const float* __restrict__ bk,
    const float* __restrict__ bv, const float* __restrict__ bo,
    unsigned short* __restrict__ Qb, unsigned short* __restrict__ Kb,
    unsigned short* __restrict__ VTb, float* __restrict__ outf, int zbase) {
  __shared__ unsigned short Al[2][128 * 64];  // 16 KB each
  __shared__ unsigned short Bl[2][64 * 64];   // 8 KB each
  int op = blockIdx.z + zbase;
  const unsigned short* A = (op == 0) ? xb : (op == 3 ? Attb : eb);
  const unsigned short* W = (op == 0) ? WqT : (op == 1 ? WkT : (op == 2 ? WvT : WoT));
  const float* bias = (op == 0) ? bq : (op == 1 ? bk : (op == 2 ? bv : bo));
  int lane = threadIdx.x & 63, wave = threadIdx.x >> 6;
  int quad = lane >> 4, l16 = lane & 15;
  int r8 = lane >> 3, g8 = (lane & 7) ^ r8;   // staged-chunk swizzle
  int m0 = blockIdx.x * 128, n0 = blockIdx.y * 64;
  const unsigned short* Ag = A + (size_t)m0 * CC + g8 * 8;
  const unsigned short* Wg = W + (size_t)n0 * CC + g8 * 8;
  f4v acc[2][4];
#pragma unroll
  for (int s = 0; s < 2; s++)
#pragma unroll
    for (int n = 0; n < 4; n++) acc[s][n] = (f4v){0, 0, 0, 0};
  // stage k-tile 0 into buf 0
#pragma unroll
  for (int j = 0; j < 4; j++)
    gll16(Ag + (size_t)(wave * 32 + j * 8 + r8) * CC, &Al[0][(wave * 32 + j * 8) * 64]);
#pragma unroll
  for (int j = 0; j < 2; j++)
    gll16(Wg + (size_t)(wave * 16 + j * 8 + r8) * CC, &Bl[0][(wave * 16 + j * 8) * 64]);
  int buf = 0;
  for (int k0 = 0; k0 < CC; k0 += 64) {
    __syncthreads();   // stage(k0) done; all waves finished reading buf^1
    if (k0 + 64 < CC) {
#pragma unroll
      for (int j = 0; j < 4; j++)
        gll16(Ag + (size_t)(wave * 32 + j * 8 + r8) * CC + k0 + 64,
              &Al[buf ^ 1][(wave * 32 + j * 8) * 64]);
#pragma unroll
      for (int j = 0; j < 2; j++)
        gll16(Wg + (size_t)(wave * 16 + j * 8 + r8) * CC + k0 + 64,
              &Bl[buf ^ 1][(wave * 16 + j * 8) * 64]);
    }
    int sw = (quad ^ (l16 & 7)) * 8;   // frag-read swizzle (shorts)
    bf8v af[2][2], bf[4][2];
#pragma unroll
    for (int sub = 0; sub < 2; sub++)
#pragma unroll
      for (int kk = 0; kk < 2; kk++)
        af[sub][kk] = ld_bf8(&Al[buf][(wave * 32 + sub * 16 + l16) * 64 + (sw ^ (kk * 32))]);
#pragma unroll
    for (int nt = 0; nt < 4; nt++)
#pragma unroll
      for (int kk = 0; kk < 2; kk++)
        bf[nt][kk] = ld_bf8(&Bl[buf][(nt * 16 + l16) * 64 + (sw ^ (kk * 32))]);
#pragma unroll
    for (int kk = 0; kk < 2; kk++)
#pragma unroll
      for (int sub = 0; sub < 2; sub++)
#pragma unroll
        for (int nt = 0; nt < 4; nt++)
          acc[sub][nt] = mfma16(af[sub][kk], bf[nt][kk], acc[sub][nt]);
    buf ^= 1;
  }
  const float QSC = 0.125f * 1.44269504088896340736f;  // exp2-domain scale
#pragma unroll
  for (int sub = 0; sub < 2; sub++) {
    int row0 = m0 + wave * 32 + sub * 16 + quad * 4;
#pragma unroll
    for (int nt = 0; nt < 4; nt++) {
      int col = n0 + nt * 16 + l16;
      float bcol = bias[col];
      if (op == 3) {
#pragma unroll
        for (int r = 0; r < 4; r++)
          outf[(size_t)(row0 + r) * CC + col] = acc[sub][nt][r] + bcol;
      } else if (op == 2) {
        int bb = row0 >> 11, tt = row0 & (TT - 1);
        us4 pk;
#pragma unroll
        for (int r = 0; r < 4; r++) pk[r] = f2bf(acc[sub][nt][r] + bcol);
        *(us4*)(VTb + ((size_t)bb * CC + col) * TS + tt) = pk;
      } else {
        unsigned short* O = (op == 0) ? Qb : Kb;
        float sc = (op == 0) ? QSC : 1.0f;
#pragma unroll
        for (int r = 0; r < 4; r++)
          O[(size_t)(row0 + r) * CC + col] = f2bf((acc[sub][nt][r] + bcol) * sc);
      }
    }
  }
}

// ---------------- flash attention, gll-staged K/V, XCD-pinned ----------------
// grid 1024: id = bh | (qblk<<4) | (chunk<<8); id%8==bh%8 pins (b,h) to one XCD.
// WG = 128 q x one (b,h) x 512-key chunk; wave owns 32 q (2 subtiles of 16).
__global__ __launch_bounds__(256) void attn_k(const unsigned short* __restrict__ Q,
    const unsigned short* __restrict__ K, const unsigned short* __restrict__ VT,
    const float* __restrict__ pinf, unsigned short* __restrict__ Op,
    float* __restrict__ Lp) {
  __shared__ unsigned short Kl[2][64 * 64];   // 8 KB each: [key][dim] rows of 128B
  __shared__ unsigned short Vl[2][64 * 64];   // 8 KB each: [dim][key]
  __shared__ unsigned short Pl[4][16][72];    // wave-private P[q][key], +8 pad
  int lane = threadIdx.x & 63, wave = threadIdx.x >> 6;
  int quad = lane >> 4, l16 = lane & 15;
  int r8 = lane >> 3, g8 = (lane & 7) ^ r8;
  int id = blockIdx.x;
  int bh = id & 15, qblk = (id >> 4) & 15, chunk = id >> 8;
  int b = bh >> 3, h = bh & 7;
  int q0 = qblk * 128 + wave * 32;
  int ck0 = chunk * KCH;

  bf8v qa[2][2];
#pragma unroll
  for (int sub = 0; sub < 2; sub++) {
    const unsigned short* qp =
        Q + (size_t)(b * TT + q0 + sub * 16 + l16) * CC + h * HD + quad * 8;
    qa[sub][0] = ld_bf8(qp);
    qa[sub][1] = ld_bf8(qp + 32);
  }

  f4v o[2][4];
#pragma unroll
  for (int s = 0; s < 2; s++)
#pragma unroll
    for (int d = 0; d < 4; d++) o[s][d] = (f4v){0, 0, 0, 0};
  f4v ls[2] = {{0, 0, 0, 0}, {0, 0, 0, 0}};
  const float* prow = pinf + (size_t)b * TS + ck0;
  const unsigned short* Kg = K + (size_t)(b * TS + ck0) * CC + h * HD + g8 * 8;
  const unsigned short* Vg = VT + ((size_t)b * CC + h * HD) * TS + ck0 + g8 * 8;

  // stage tile 0 into buf 0
#pragma unroll
  for (int j = 0; j < 2; j++) {
    int row = wave * 16 + j * 8;
    gll16(Kg + (size_t)(row + r8) * CC, &Kl[0][row * 64]);
    gll16(Vg + (size_t)(row + r8) * TS, &Vl[0][row * 64]);
  }
  int buf = 0;
  for (int kt = 0; kt < KCH; kt += 64) {
    __syncthreads();   // stage(kt) done; all waves finished reading buf^1
    if (kt + 64 < KCH) {
#pragma unroll
      for (int j = 0; j < 2; j++) {
        int row = wave * 16 + j * 8;
        gll16(Kg + (size_t)(kt + 64 + row + r8) * CC, &Kl[buf ^ 1][row * 64]);
        gll16(Vg + (size_t)(row + r8) * TS + kt + 64, &Vl[buf ^ 1][row * 64]);
      }
    }
    int sw = (quad ^ (l16 & 7)) * 8;
    bf8v kf[4][2];
#pragma unroll
    for (int nt = 0; nt < 4; nt++) {
      kf[nt][0] = ld_bf8(&Kl[buf][(nt * 16 + l16) * 64 + sw]);
      kf[nt][1] = ld_bf8(&Kl[buf][(nt * 16 + l16) * 64 + (sw ^ 32)]);
    }
#pragma unroll
    for (int sub = 0; sub < 2; sub++) {
      // S^T = K.Q^T + pen (log2 domain; penalty as accumulator init)
      f4v s[4];
#pragma unroll
      for (int nt = 0; nt < 4; nt++) {
        f4v z = *(const f4v*)(prow + kt + nt * 16 + quad * 4);
        z = mfma16(kf[nt][0], qa[sub][0], z);
        z = mfma16(kf[nt][1], qa[sub][1], z);
        s[nt] = z;
      }
      // max-free softmax: P = exp2(s); l accumulated per-lane
#pragma unroll
      for (int nt = 0; nt < 4; nt++) {
        us4 pk;
#pragma unroll
        for (int r = 0; r < 4; r++) {
          float p = __builtin_amdgcn_exp2f(s[nt][r]);
          s[nt][r] = p;
          pk[r] = f2bf(p);
        }
        ls[sub] += s[nt];
        *(us4*)&Pl[wave][l16][nt * 16 + quad * 4] = pk;
      }
      bf8v pb0 = ld_bf8(&Pl[wave][l16][quad * 8]);
      bf8v pb1 = ld_bf8(&Pl[wave][l16][32 + quad * 8]);
      // O^T += V^T.P^T (V frags from LDS at use)
#pragma unroll
      for (int dt = 0; dt < 4; dt++) {
        bf8v v0 = ld_bf8(&Vl[buf][(dt * 16 + l16) * 64 + sw]);
        bf8v v1 = ld_bf8(&Vl[buf][(dt * 16 + l16) * 64 + (sw ^ 32)]);
        o[sub][dt] = mfma16(v0, pb0, o[sub][dt]);
        o[sub][dt] = mfma16(v1, pb1, o[sub][dt]);
      }
    }
    buf ^= 1;
  }
  // epilogue: unnormalized partials + per-chunk l
#pragma unroll
  for (int sub = 0; sub < 2; sub++) {
    float l = (ls[sub][0] + ls[sub][1]) + (ls[sub][2] + ls[sub][3]);
    l += __shfl_xor(l, 16, 64);
    l += __shfl_xor(l, 32, 64);
    int rowb = (b * NH + h) * TT + q0 + sub * 16;
    size_t obase = (size_t)chunk * NROW * HD + (size_t)(rowb + l16) * HD;
#pragma unroll
    for (int dt = 0; dt < 4; dt++) {
      us4 pk;
#pragma unroll
      for (int r = 0; r < 4; r++) pk[r] = f2bf(o[sub][dt][r]);
      *(us4*)&Op[obase + dt * 16 + quad * 4] = pk;
    }
    if (quad == 0) Lp[(size_t)chunk * NROW + rowb + l16] = l;
  }
}

// ---------------- split-K combine: plain sums (shared exp2 domain) ----------------
__global__ __launch_bounds__(256) void combine_k(const unsigned short* __restrict__ Op,
    const float* __restrict__ Lp, unsigned short* __restrict__ Attb) {
  int row = blockIdx.x * 4 + (threadIdx.x >> 6);
  int d = threadIdx.x & 63;
  float L = 0.f, o = 0.f;
#pragma unroll
  for (int c = 0; c < NCH; c++) {
    L += Lp[(size_t)c * NROW + row];
    o += bf2f(Op[(size_t)c * NROW * HD + (size_t)row * HD + d]);
  }
  int b = row >> 14, h = (row >> 11) & 7, q = row & (TT - 1);
  Attb[((size_t)(b * TT + q)) * CC + h * HD + d] = f2bf(o / L);
}

extern "C" void kernel_launch(void* const* d_in, const int* in_sizes, int n_in,
                              void* d_out, int out_size, void* d_ws, size_t ws_size,
                              hipStream_t stream) {
  const float* x   = (const float*)d_in[0];
  const float* enc = (const float*)d_in[1];
  const int*   msk = (const int*)d_in[2];
  const float* Wq  = (const float*)d_in[3];
  const float* bq  = (const float*)d_in[4];
  const float* Wk  = (const float*)d_in[5];
  const float* bk  = (const float*)d_in[6];
  const float* Wv  = (const float*)d_in[7];
  const float* bv  = (const float*)d_in[8];
  const float* Wo  = (const float*)d_in[9];
  const float* bo  = (const float*)d_in[10];
  float* out = (float*)d_out;

  char* ws = (char*)d_ws;
  const size_t MB = 1024 * 1024;
  unsigned short* WqT  = (unsigned short*)(ws);                 // 512 KB
  unsigned short* WkT  = (unsigned short*)(ws + 512 * 1024);
  unsigned short* WvT  = (unsigned short*)(ws + 1024 * 1024);
  unsigned short* WoT  = (unsigned short*)(ws + 1536 * 1024);
  unsigned short* Qb   = (unsigned short*)(ws + 2 * MB);        // 4 MB
  unsigned short* Kb   = (unsigned short*)(ws + 6 * MB);        // 4 MB
  unsigned short* VTb  = (unsigned short*)(ws + 10 * MB);       // 4 MB
  unsigned short* Attb = (unsigned short*)(ws + 14 * MB);       // 4 MB
  // xb/eb live only until the QKV GEMM; Opart overlays them afterwards
  unsigned short* xb   = (unsigned short*)(ws + 18 * MB);       // 4 MB
  unsigned short* eb   = (unsigned short*)(ws + 22 * MB);       // 4 MB
  unsigned short* Opart = (unsigned short*)(ws + 18 * MB);      // 16 MB (overlay)
  float* Lp   = (float*)(ws + 34 * MB);                         // 512 KB
  float* pinf = (float*)(ws + 35 * MB);                         // 16 KB

  dim3 blk(256);
  wtrans_k<<<dim3(8, 8, 4), blk, 0, stream>>>(Wq, Wk, Wv, Wo, WqT, WkT, WvT, WoT);
  cvt_k<<<dim3(2048), blk, 0, stream>>>(x, enc, msk, xb, eb, pinf);

  // QKV projections (z = 0,1,2)
  gemm128_k<<<dim3(32, 8, 3), blk, 0, stream>>>(xb, eb, Attb, WqT, WkT, WvT, WoT,
                                                bq, bk, bv, bo, Qb, Kb, VTb, out, 0);

  attn_k<<<dim3(1024), blk, 0, stream>>>(Qb, Kb, VTb, pinf, Opart, Lp);
  combine_k<<<dim3(NROW / 4), blk, 0, stream>>>(Opart, Lp, Attb);

  // output projection (op = 3)
  gemm128_k<<<dim3(32, 8, 1), blk, 0, stream>>>(xb, eb, Attb, WqT, WkT, WvT, WoT,
                                                bq, bk, bv, bo, Qb, Kb, VTb, out, 3);
}

// Round 8
// 145.119 us; speedup vs baseline: 2.0940x; 1.0489x over previous
//
#include <hip/hip_runtime.h>

#define TT 2048
#define TS 2048
#define NB 2
#define CC 512
#define NH 8
#define HD 64
#define NCH 2                 // split-K chunks over keys
#define KCH (TS / NCH)        // 1024 keys per chunk
#define NROW (NB * NH * TT)   // 32768 (b,h,q) rows

typedef __attribute__((ext_vector_type(8))) short s8v;
typedef __attribute__((ext_vector_type(8))) __bf16 bf8v;
typedef __attribute__((ext_vector_type(4))) float f4v;
typedef __attribute__((ext_vector_type(4))) unsigned short us4;

static __device__ __forceinline__ unsigned short f2bf(float f) {
  unsigned int u = __builtin_bit_cast(unsigned int, f);
  u += 0x7FFFu + ((u >> 16) & 1u);   // round-to-nearest-even
  return (unsigned short)(u >> 16);
}
static __device__ __forceinline__ float bf2f(unsigned short u) {
  return __builtin_bit_cast(float, (unsigned int)u << 16);
}
static __device__ __forceinline__ bf8v ld_bf8(const unsigned short* p) {
  return __builtin_bit_cast(bf8v, *(const s8v*)p);
}
static __device__ __forceinline__ f4v mfma16(bf8v a, bf8v b, f4v c) {
  return __builtin_amdgcn_mfma_f32_16x16x32_bf16(a, b, c, 0, 0, 0);
}
// async global->LDS, 16B per lane. LDS dest = wave-uniform base + lane*16.
static __device__ __forceinline__ void gll16(const unsigned short* g,
                                             unsigned short* l) {
  __builtin_amdgcn_global_load_lds(
      (const __attribute__((address_space(1))) unsigned int*)g,
      (__attribute__((address_space(3))) unsigned int*)l, 16, 0, 0);
}

// ---------------- prep: weight transpose (id<256) | activation cvt + pinf ----------------
__global__ __launch_bounds__(256) void prep_k(const float* __restrict__ W0,
    const float* __restrict__ W1, const float* __restrict__ W2, const float* __restrict__ W3,
    unsigned short* __restrict__ T0, unsigned short* __restrict__ T1,
    unsigned short* __restrict__ T2, unsigned short* __restrict__ T3,
    const float* __restrict__ x, const float* __restrict__ enc,
    const int* __restrict__ mask, unsigned short* __restrict__ xb,
    unsigned short* __restrict__ eb, float* __restrict__ pinf) {
  __shared__ float t[64][65];
  int id = blockIdx.x;
  if (id < 256) {
    const float* Ws[4] = {W0, W1, W2, W3};
    unsigned short* Ts[4] = {T0, T1, T2, T3};
    const float* W = Ws[id >> 6];
    unsigned short* WT = Ts[id >> 6];
    int blk = id & 63;
    int i0 = (blk >> 3) * 64, j0 = (blk & 7) * 64;
    int tx = threadIdx.x & 63, ty = threadIdx.x >> 6;
#pragma unroll
    for (int r = 0; r < 16; r++) {
      int li = ty * 16 + r;
      t[li][tx] = W[(size_t)(i0 + li) * CC + j0 + tx];
    }
    __syncthreads();
#pragma unroll
    for (int r = 0; r < 16; r++) {
      int lj = ty * 16 + r;
      WT[(size_t)(j0 + lj) * CC + i0 + tx] = f2bf(t[tx][lj]);
    }
  } else {
    size_t tt = (size_t)(id - 256) * 256 + threadIdx.x;
    size_t i = tt * 4;
    f4v a = *(const f4v*)(x + i);
    f4v b = *(const f4v*)(enc + i);
    us4 pa, pb;
#pragma unroll
    for (int j = 0; j < 4; j++) { pa[j] = f2bf(a[j]); pb[j] = f2bf(b[j]); }
    *(us4*)(xb + i) = pa;
    *(us4*)(eb + i) = pb;
    if (tt < NB * TS) pinf[tt] = (mask[tt] != 0) ? 0.0f : -1e30f;
  }
}

// ---------------- 128x64-tile QKV GEMM, gll-staged, double-buffered LDS ----------------
// op = blockIdx.z: 0=Q (exp2 scale), 1=K, 2=V (transposed store)
__global__ __launch_bounds__(256) void qkv_k(
    const unsigned short* __restrict__ xb, const unsigned short* __restrict__ eb,
    const unsigned short* __restrict__ WqT, const unsigned short* __restrict__ WkT,
    const unsigned short* __restrict__ WvT,
    const float* __restrict__ bq, const float* __restrict__ bk,
    const float* __restrict__ bv,
    unsigned short* __restrict__ Qb, unsigned short* __restrict__ Kb,
    unsigned short* __restrict__ VTb) {
  __shared__ unsigned short Al[2][128 * 64];  // 16 KB each
  __shared__ unsigned short Bl[2][64 * 64];   // 8 KB each
  int op = blockIdx.z;
  const unsigned short* A = (op == 0) ? xb : eb;
  const unsigned short* W = (op == 0) ? WqT : (op == 1 ? WkT : WvT);
  const float* bias = (op == 0) ? bq : (op == 1 ? bk : bv);
  int lane = threadIdx.x & 63, wave = threadIdx.x >> 6;
  int quad = lane >> 4, l16 = lane & 15;
  int r8 = lane >> 3, g8 = (lane & 7) ^ r8;   // staged-chunk swizzle
  int m0 = blockIdx.x * 128, n0 = blockIdx.y * 64;
  const unsigned short* Ag = A + (size_t)m0 * CC + g8 * 8;
  const unsigned short* Wg = W + (size_t)n0 * CC + g8 * 8;
  f4v acc[2][4];
#pragma unroll
  for (int s = 0; s < 2; s++)
#pragma unroll
    for (int n = 0; n < 4; n++) acc[s][n] = (f4v){0, 0, 0, 0};
#pragma unroll
  for (int j = 0; j < 4; j++)
    gll16(Ag + (size_t)(wave * 32 + j * 8 + r8) * CC, &Al[0][(wave * 32 + j * 8) * 64]);
#pragma unroll
  for (int j = 0; j < 2; j++)
    gll16(Wg + (size_t)(wave * 16 + j * 8 + r8) * CC, &Bl[0][(wave * 16 + j * 8) * 64]);
  int buf = 0;
  for (int k0 = 0; k0 < CC; k0 += 64) {
    __syncthreads();
    if (k0 + 64 < CC) {
#pragma unroll
      for (int j = 0; j < 4; j++)
        gll16(Ag + (size_t)(wave * 32 + j * 8 + r8) * CC + k0 + 64,
              &Al[buf ^ 1][(wave * 32 + j * 8) * 64]);
#pragma unroll
      for (int j = 0; j < 2; j++)
        gll16(Wg + (size_t)(wave * 16 + j * 8 + r8) * CC + k0 + 64,
              &Bl[buf ^ 1][(wave * 16 + j * 8) * 64]);
    }
    int sw = (quad ^ (l16 & 7)) * 8;
    bf8v af[2][2], bfr[4][2];
#pragma unroll
    for (int sub = 0; sub < 2; sub++)
#pragma unroll
      for (int kk = 0; kk < 2; kk++)
        af[sub][kk] = ld_bf8(&Al[buf][(wave * 32 + sub * 16 + l16) * 64 + (sw ^ (kk * 32))]);
#pragma unroll
    for (int nt = 0; nt < 4; nt++)
#pragma unroll
      for (int kk = 0; kk < 2; kk++)
        bfr[nt][kk] = ld_bf8(&Bl[buf][(nt * 16 + l16) * 64 + (sw ^ (kk * 32))]);
#pragma unroll
    for (int kk = 0; kk < 2; kk++)
#pragma unroll
      for (int sub = 0; sub < 2; sub++)
#pragma unroll
        for (int nt = 0; nt < 4; nt++)
          acc[sub][nt] = mfma16(af[sub][kk], bfr[nt][kk], acc[sub][nt]);
    buf ^= 1;
  }
  const float QSC = 0.125f * 1.44269504088896340736f;  // exp2-domain scale
#pragma unroll
  for (int sub = 0; sub < 2; sub++) {
    int row0 = m0 + wave * 32 + sub * 16 + quad * 4;
#pragma unroll
    for (int nt = 0; nt < 4; nt++) {
      int col = n0 + nt * 16 + l16;
      float bcol = bias[col];
      if (op == 2) {
        int bb = row0 >> 11, tt = row0 & (TT - 1);
        us4 pk;
#pragma unroll
        for (int r = 0; r < 4; r++) pk[r] = f2bf(acc[sub][nt][r] + bcol);
        *(us4*)(VTb + ((size_t)bb * CC + col) * TS + tt) = pk;
      } else {
        unsigned short* O = (op == 0) ? Qb : Kb;
        float sc = (op == 0) ? QSC : 1.0f;
#pragma unroll
        for (int r = 0; r < 4; r++)
          O[(size_t)(row0 + r) * CC + col] = f2bf((acc[sub][nt][r] + bcol) * sc);
      }
    }
  }
}

// ---------------- flash attention, gll-staged K/V, XCD-pinned, NCH=2 ----------------
// grid 512: id = bh | (qblk<<4) | (chunk<<8); id%8==bh%8 pins (b,h) to one XCD.
__global__ __launch_bounds__(256) void attn_k(const unsigned short* __restrict__ Q,
    const unsigned short* __restrict__ K, const unsigned short* __restrict__ VT,
    const float* __restrict__ pinf, unsigned short* __restrict__ Op,
    float* __restrict__ Lp) {
  __shared__ unsigned short Kl[2][64 * 64];   // 8 KB each
  __shared__ unsigned short Vl[2][64 * 64];   // 8 KB each
  __shared__ unsigned short Pl[4][2][16 * 72];  // wave-private, dbuf by sub
  int lane = threadIdx.x & 63, wave = threadIdx.x >> 6;
  int quad = lane >> 4, l16 = lane & 15;
  int r8 = lane >> 3, g8 = (lane & 7) ^ r8;
  int id = blockIdx.x;
  int bh = id & 15, qblk = (id >> 4) & 15, chunk = id >> 8;
  int b = bh >> 3, h = bh & 7;
  int q0 = qblk * 128 + wave * 32;
  int ck0 = chunk * KCH;

  bf8v qa[2][2];
#pragma unroll
  for (int sub = 0; sub < 2; sub++) {
    const unsigned short* qp =
        Q + (size_t)(b * TT + q0 + sub * 16 + l16) * CC + h * HD + quad * 8;
    qa[sub][0] = ld_bf8(qp);
    qa[sub][1] = ld_bf8(qp + 32);
  }

  f4v o[2][4];
#pragma unroll
  for (int s = 0; s < 2; s++)
#pragma unroll
    for (int d = 0; d < 4; d++) o[s][d] = (f4v){0, 0, 0, 0};
  f4v ls[2] = {{0, 0, 0, 0}, {0, 0, 0, 0}};
  const float* prow = pinf + (size_t)b * TS + ck0;
  const unsigned short* Kg = K + (size_t)(b * TS + ck0) * CC + h * HD + g8 * 8;
  const unsigned short* Vg = VT + ((size_t)b * CC + h * HD) * TS + ck0 + g8 * 8;

#pragma unroll
  for (int j = 0; j < 2; j++) {
    int row = wave * 16 + j * 8;
    gll16(Kg + (size_t)(row + r8) * CC, &Kl[0][row * 64]);
    gll16(Vg + (size_t)(row + r8) * TS, &Vl[0][row * 64]);
  }
  int buf = 0;
  for (int kt = 0; kt < KCH; kt += 64) {
    __syncthreads();
    if (kt + 64 < KCH) {
#pragma unroll
      for (int j = 0; j < 2; j++) {
        int row = wave * 16 + j * 8;
        gll16(Kg + (size_t)(kt + 64 + row + r8) * CC, &Kl[buf ^ 1][row * 64]);
        gll16(Vg + (size_t)(row + r8) * TS + kt + 64, &Vl[buf ^ 1][row * 64]);
      }
    }
    int sw = (quad ^ (l16 & 7)) * 8;
    bf8v kf[4][2], vf[4][2];
#pragma unroll
    for (int nt = 0; nt < 4; nt++) {
      kf[nt][0] = ld_bf8(&Kl[buf][(nt * 16 + l16) * 64 + sw]);
      kf[nt][1] = ld_bf8(&Kl[buf][(nt * 16 + l16) * 64 + (sw ^ 32)]);
      vf[nt][0] = ld_bf8(&Vl[buf][(nt * 16 + l16) * 64 + sw]);
      vf[nt][1] = ld_bf8(&Vl[buf][(nt * 16 + l16) * 64 + (sw ^ 32)]);
    }
#pragma unroll
    for (int sub = 0; sub < 2; sub++) {
      // S^T = K.Q^T + pen (log2 domain; penalty as accumulator init)
      f4v s[4];
#pragma unroll
      for (int nt = 0; nt < 4; nt++) {
        f4v z = *(const f4v*)(prow + kt + nt * 16 + quad * 4);
        z = mfma16(kf[nt][0], qa[sub][0], z);
        z = mfma16(kf[nt][1], qa[sub][1], z);
        s[nt] = z;
      }
      // max-free softmax: P = exp2(s); l accumulated per-lane
      unsigned short* pw = &Pl[wave][sub][0];
#pragma unroll
      for (int nt = 0; nt < 4; nt++) {
        us4 pk;
#pragma unroll
        for (int r = 0; r < 4; r++) {
          float p = __builtin_amdgcn_exp2f(s[nt][r]);
          s[nt][r] = p;
          pk[r] = f2bf(p);
        }
        ls[sub] += s[nt];
        *(us4*)&pw[l16 * 72 + nt * 16 + quad * 4] = pk;
      }
      bf8v pb0 = ld_bf8(&pw[l16 * 72 + quad * 8]);
      bf8v pb1 = ld_bf8(&pw[l16 * 72 + 32 + quad * 8]);
      // O^T += V^T.P^T
#pragma unroll
      for (int dt = 0; dt < 4; dt++) {
        o[sub][dt] = mfma16(vf[dt][0], pb0, o[sub][dt]);
        o[sub][dt] = mfma16(vf[dt][1], pb1, o[sub][dt]);
      }
    }
    buf ^= 1;
  }
  // epilogue: unnormalized partials + per-chunk l
#pragma unroll
  for (int sub = 0; sub < 2; sub++) {
    float l = (ls[sub][0] + ls[sub][1]) + (ls[sub][2] + ls[sub][3]);
    l += __shfl_xor(l, 16, 64);
    l += __shfl_xor(l, 32, 64);
    int rowb = (b * NH + h) * TT + q0 + sub * 16;
    size_t obase = (size_t)chunk * NROW * HD + (size_t)(rowb + l16) * HD;
#pragma unroll
    for (int dt = 0; dt < 4; dt++) {
      us4 pk;
#pragma unroll
      for (int r = 0; r < 4; r++) pk[r] = f2bf(o[sub][dt][r]);
      *(us4*)&Op[obase + dt * 16 + quad * 4] = pk;
    }
    if (quad == 0) Lp[(size_t)chunk * NROW + rowb + l16] = l;
  }
}

// ---------------- output projection with fused split-K combine ----------------
// A-tile staged by reading both Opart chunks + Lp, combining, ds_write (base+lane*16).
__global__ __launch_bounds__(256) void gemmo_k(const unsigned short* __restrict__ Op,
    const float* __restrict__ Lp, const unsigned short* __restrict__ WoT,
    const float* __restrict__ bo, float* __restrict__ outf) {
  __shared__ unsigned short Al[2][128 * 64];
  __shared__ unsigned short Bl[2][64 * 64];
  int lane = threadIdx.x & 63, wave = threadIdx.x >> 6;
  int quad = lane >> 4, l16 = lane & 15;
  int r8 = lane >> 3, lc = lane & 7, g8 = lc ^ r8;
  int m0 = blockIdx.x * 128, n0 = blockIdx.y * 64;
  const unsigned short* Wg = WoT + (size_t)n0 * CC + g8 * 8;
  f4v acc[2][4];
#pragma unroll
  for (int s = 0; s < 2; s++)
#pragma unroll
    for (int n = 0; n < 4; n++) acc[s][n] = (f4v){0, 0, 0, 0};

  auto stage_a = [&](int k0, int dbuf) {
    int h = k0 >> 6;
#pragma unroll
    for (int j = 0; j < 4; j++) {
      int rr = wave * 32 + j * 8 + r8;
      int m = m0 + rr;
      int bb = m >> 11, q = m & (TT - 1);
      size_t rowb = (size_t)((bb * NH + h) * TT + q);
      int gd = (lc ^ r8) * 8;
      s8v o0 = *(const s8v*)(Op + rowb * HD + gd);
      s8v o1 = *(const s8v*)(Op + (size_t)NROW * HD + rowb * HD + gd);
      float L = Lp[rowb] + Lp[NROW + rowb];
      float inv = __builtin_amdgcn_rcpf(L);
      s8v pk;
#pragma unroll
      for (int e = 0; e < 8; e++) {
        float v = (bf2f((unsigned short)o0[e]) + bf2f((unsigned short)o1[e])) * inv;
        pk[e] = (short)f2bf(v);
      }
      *(s8v*)&Al[dbuf][rr * 64 + lc * 8] = pk;  // addr = base + lane*16: conflict-free
    }
  };

  stage_a(0, 0);
#pragma unroll
  for (int j = 0; j < 2; j++)
    gll16(Wg + (size_t)(wave * 16 + j * 8 + r8) * CC, &Bl[0][(wave * 16 + j * 8) * 64]);
  int buf = 0;
  for (int k0 = 0; k0 < CC; k0 += 64) {
    __syncthreads();
    if (k0 + 64 < CC) {
      stage_a(k0 + 64, buf ^ 1);
#pragma unroll
      for (int j = 0; j < 2; j++)
        gll16(Wg + (size_t)(wave * 16 + j * 8 + r8) * CC + k0 + 64,
              &Bl[buf ^ 1][(wave * 16 + j * 8) * 64]);
    }
    int sw = (quad ^ (l16 & 7)) * 8;
    bf8v af[2][2], bfr[4][2];
#pragma unroll
    for (int sub = 0; sub < 2; sub++)
#pragma unroll
      for (int kk = 0; kk < 2; kk++)
        af[sub][kk] = ld_bf8(&Al[buf][(wave * 32 + sub * 16 + l16) * 64 + (sw ^ (kk * 32))]);
#pragma unroll
    for (int nt = 0; nt < 4; nt++)
#pragma unroll
      for (int kk = 0; kk < 2; kk++)
        bfr[nt][kk] = ld_bf8(&Bl[buf][(nt * 16 + l16) * 64 + (sw ^ (kk * 32))]);
#pragma unroll
    for (int kk = 0; kk < 2; kk++)
#pragma unroll
      for (int sub = 0; sub < 2; sub++)
#pragma unroll
        for (int nt = 0; nt < 4; nt++)
          acc[sub][nt] = mfma16(af[sub][kk], bfr[nt][kk], acc[sub][nt]);
    buf ^= 1;
  }
#pragma unroll
  for (int sub = 0; sub < 2; sub++) {
    int row0 = m0 + wave * 32 + sub * 16 + quad * 4;
#pragma unroll
    for (int nt = 0; nt < 4; nt++) {
      int col = n0 + nt * 16 + l16;
      float bcol = bo[col];
#pragma unroll
      for (int r = 0; r < 4; r++)
        outf[(size_t)(row0 + r) * CC + col] = acc[sub][nt][r] + bcol;
    }
  }
}

extern "C" void kernel_launch(void* const* d_in, const int* in_sizes, int n_in,
                              void* d_out, int out_size, void* d_ws, size_t ws_size,
                              hipStream_t stream) {
  const float* x   = (const float*)d_in[0];
  const float* enc = (const float*)d_in[1];
  const int*   msk = (const int*)d_in[2];
  const float* Wq  = (const float*)d_in[3];
  const float* bq  = (const float*)d_in[4];
  const float* Wk  = (const float*)d_in[5];
  const float* bk  = (const float*)d_in[6];
  const float* Wv  = (const float*)d_in[7];
  const float* bv  = (const float*)d_in[8];
  const float* Wo  = (const float*)d_in[9];
  const float* bo  = (const float*)d_in[10];
  float* out = (float*)d_out;

  char* ws = (char*)d_ws;
  const size_t MB = 1024 * 1024;
  unsigned short* WqT  = (unsigned short*)(ws);                 // 512 KB
  unsigned short* WkT  = (unsigned short*)(ws + 512 * 1024);
  unsigned short* WvT  = (unsigned short*)(ws + 1024 * 1024);
  unsigned short* WoT  = (unsigned short*)(ws + 1536 * 1024);
  unsigned short* Qb   = (unsigned short*)(ws + 2 * MB);        // 4 MB
  unsigned short* Kb   = (unsigned short*)(ws + 6 * MB);        // 4 MB
  unsigned short* VTb  = (unsigned short*)(ws + 10 * MB);       // 4 MB
  // xb/eb live only until the QKV GEMM; Opart (8 MB, NCH=2) overlays them
  unsigned short* xb   = (unsigned short*)(ws + 18 * MB);       // 4 MB
  unsigned short* eb   = (unsigned short*)(ws + 22 * MB);       // 4 MB
  unsigned short* Opart = (unsigned short*)(ws + 18 * MB);      // 8 MB (overlay)
  float* Lp   = (float*)(ws + 34 * MB);                         // 256 KB
  float* pinf = (float*)(ws + 35 * MB);                         // 16 KB

  dim3 blk(256);
  prep_k<<<dim3(2304), blk, 0, stream>>>(Wq, Wk, Wv, Wo, WqT, WkT, WvT, WoT,
                                         x, enc, msk, xb, eb, pinf);

  qkv_k<<<dim3(32, 8, 3), blk, 0, stream>>>(xb, eb, WqT, WkT, WvT,
                                            bq, bk, bv, Qb, Kb, VTb);

  attn_k<<<dim3(512), blk, 0, stream>>>(Qb, Kb, VTb, pinf, Opart, Lp);

  gemmo_k<<<dim3(32, 8), blk, 0, stream>>>(Opart, Lp, WoT, bo, out);
}